// Round 10
// baseline (852.233 us; speedup 1.0000x reference)
//
#include <hip/hip_runtime.h>
#include <stdint.h>

#define DD 50
#define TT 1024
#define NB 16            // batch rows per block = MFMA M (full tile)
#define KF 32            // x-prefetch / out-flush chunk (steps)

typedef _Float16 half_t;
typedef __attribute__((ext_vector_type(8))) _Float16 f16x8;
typedef __attribute__((ext_vector_type(4))) float    f32x4;

#define AHS 72           // K=64: h1(50)|x(2)|1@52|0|h2[48]@54|h2[49]@55|pad — 144B rows
#define A2S 72           // K=64: h2(48) | pad (k48..63 always zero)
#define OBW 68           // obuf row stride (f32)

__device__ __forceinline__ float rcp_f(float x)  { return __builtin_amdgcn_rcpf(x); }
__device__ __forceinline__ float exp2_f(float x) { return __builtin_amdgcn_exp2f(x); }

// Fused LSTM cell update, common-denominator form: 5 exp2 + 2 rcp.
//   cn = [c*(1+a)(1+b) + (1+f_)(b-1)] / [(1+f_)(1+a)(1+b)]
//   h  = (e-1) / [(1+o_)(1+e)],  a=e^-i, b=e^{2g}, f_=e^-f, o_=e^-o, e=e^{2cn}
__device__ __forceinline__ float cell_update(const f32x4 acc, float& c) {
    const float a  = exp2_f(-1.4426950f * acc[0]);
    const float b  = exp2_f( 2.8853901f * acc[2]);
    const float f_ = exp2_f(-1.4426950f * acc[1]);
    const float uv = (1.0f + a) * (1.0f + b);
    const float wf = 1.0f + f_;
    const float cn = (c * uv + wf * (b - 1.0f)) * rcp_f(wf * uv);
    c = cn;
    const float o_ = exp2_f(-1.4426950f * acc[3]);
    const float e  = exp2_f( 2.8853901f * cn);
    return (e - 1.0f) * rcp_f((1.0f + o_) * (1.0f + e));
}

// 16 waves: waves 0-12 own ONE 16-col N-tile each (tile 12 = jj 48,49 + head
// cols 200,201); waves 13-15 service-only. col' = 4*jj + gate; swapped-operand
// MFMA: lane (cl,g2) holds acc[r] = gate r of (b=cl, jj=4w+g2) — cell update
// per-lane. AH=[h1|x|1@52|h2[48,49]@54,55] feeds GEMM1 + GEMM2 kt0/1;
// A2=[h2(0..47)] feeds kt2/3 (k48..63 zero -> g2>=2 lanes skip the kt3 read;
// AH k56..63 zero -> g2==3 lanes skip the kt1 read). One barrier per interval;
// parity compile-time via 2x unroll.

__global__ __launch_bounds__(1024, 1)
void lstm_mfma_kernel(const float* __restrict__ x,
                      const float* __restrict__ W_ih1, const float* __restrict__ W_hh1,
                      const float* __restrict__ b_ih1, const float* __restrict__ b_hh1,
                      const float* __restrict__ W_ih2, const float* __restrict__ W_hh2,
                      const float* __restrict__ b_ih2, const float* __restrict__ b_hh2,
                      const float* __restrict__ W_lin, const float* __restrict__ b_lin,
                      float* __restrict__ out)
{
    const int tid  = threadIdx.x;
    const int lane = tid & 63;
    const int w    = tid >> 6;           // 0..15
    const int bg0  = blockIdx.x * NB;
    const int cl   = lane & 15;          // batch row (n)
    const int g2   = lane >> 4;          // k-group / jj offset within tile

    __shared__ half_t AH[2][NB][AHS];
    __shared__ half_t A2[2][NB][A2S];
    __shared__ float  obuf[2][NB][OBW];
    __shared__ float  xbuf[2][NB][KF*2];

    const bool isComp = (w < 13);
    const int  tile   = isComp ? w : 0;
    const int  jj     = tile * 4 + g2;
    const bool doUpd  = isComp && (jj < DD);
    const bool headLn = (w == 12) && (g2 == 2);    // lanes holding cols 200,201
    const int  xr     = (tid - 768) >> 4;          // service row (tid>=768)
    const int  xq     = tid & 15;

    // ---- B fragments (one tile per wave) ----
    f16x8 b1f[2], b2f[4];
    {
        const int  colp  = tile * 16 + cl;
        const bool valid = isComp && (colp < 200);
        const bool headB = isComp && (colp >= 200) && (colp <= 201);
        const int  g     = (colp & 3) * DD + (colp >> 2);
        // B1 over AH-k: W_hh1 | W_ih1@50,51 | bias1@52 (54,55 zero!)
#pragma unroll
        for (int kt = 0; kt < 2; ++kt)
#pragma unroll
            for (int j = 0; j < 8; ++j) {
                const int k = kt * 32 + g2 * 8 + j;
                float v = 0.f;
                if (valid) {
                    if (k < DD)          v = W_hh1[g * DD + k];
                    else if (k < DD + 2) v = W_ih1[g * 2 + (k - DD)];
                    else if (k == 52)    v = b_ih1[g] + b_hh1[g];
                }
                b1f[kt][j] = (half_t)v;
            }
        // B2 kt0/1 over AH-k: W_ih2 | 0@50,51 | bias2@52 | W_hh2[:,48]@54 | W_hh2[:,49]@55
#pragma unroll
        for (int kt = 0; kt < 2; ++kt)
#pragma unroll
            for (int j = 0; j < 8; ++j) {
                const int k = kt * 32 + g2 * 8 + j;
                float v = 0.f;
                if (k < DD) {
                    if (valid) v = W_ih2[g * DD + k];
                } else if (k == 52) {
                    if (valid)      v = b_ih2[g] + b_hh2[g];
                    else if (headB) v = b_lin[colp - 200];
                } else if (k == 54 || k == 55) {
                    const int hk = 48 + (k - 54);
                    if (valid)      v = W_hh2[g * DD + hk];
                    else if (headB) v = W_lin[(colp - 200) * DD + hk];
                }
                b2f[kt][j] = (half_t)v;
            }
        // B2 kt2/3 over A2-k (h2 at k'=0..47): W_hh2 (head: W_lin)
#pragma unroll
        for (int kt = 2; kt < 4; ++kt)
#pragma unroll
            for (int j = 0; j < 8; ++j) {
                const int kk = (kt - 2) * 32 + g2 * 8 + j;
                float v = 0.f;
                if (kk < 48) {
                    if (valid)      v = W_hh2[g * DD + kk];
                    else if (headB) v = W_lin[(colp - 200) * DD + kk];
                }
                b2f[kt][j] = (half_t)v;
            }
    }

    // ---- init ----
    for (int idx = tid; idx < 2 * NB * AHS; idx += 1024) ((half_t*)AH)[idx] = (half_t)0.f;
    for (int idx = tid; idx < 2 * NB * A2S; idx += 1024) ((half_t*)A2)[idx] = (half_t)0.f;
    if (tid >= 768) {
        const f32x4 v = *(const f32x4*)(x + (size_t)(bg0 + xr) * (TT * 2) + xq * 4);
        *(f32x4*)&xbuf[0][xr][xq * 4] = v;
    }
    __syncthreads();
    if (tid < NB) {
        AH[0][tid][52] = (half_t)1.0f; AH[1][tid][52] = (half_t)1.0f;
        AH[1][tid][50] = (half_t)xbuf[0][tid][0];    // x(0) at parity of I=-1
        AH[1][tid][51] = (half_t)xbuf[0][tid][1];
    }
    __syncthreads();

    float c1 = 0.f, c2 = 0.f;

#define LSTM_STEP(PC)                                                              \
    {                                                                               \
        constexpr int P = (PC), NP = (PC) ^ 1;                                      \
        if (((I & 31) == 1) && I >= 33 && tid >= 768) {                             \
            const f32x4 v = *(const f32x4*)&obuf[((I - 33) >> 5) & 1][xr][xq * 4];  \
            *(f32x4*)(out + (size_t)(bg0 + xr) * (TT * 2) + (I - 33) * 2 + xq * 4) = v; \
        }                                                                           \
        f32x4 xpre; bool hp = false;                                                \
        if (((I & 31) == 0) && I >= 0 && tid >= 768) {                              \
            const int chunk = (I >> 5) + 1;                                         \
            if (chunk < TT / KF) {                                                  \
                hp = true;                                                          \
                xpre = *(const f32x4*)(x + (size_t)(bg0 + xr) * (TT * 2) + chunk * (KF * 2) + xq * 4); \
            }                                                                       \
        }                                                                           \
        f32x4 acc1, acc2;                                                           \
        if (isComp) {                                                               \
            const f16x8 a0 = *(const f16x8*)&AH[P][cl][g2 * 8];                     \
            f16x8 a1 = {};                                                          \
            if (g2 < 3) a1 = *(const f16x8*)&AH[P][cl][32 + g2 * 8];                \
            const f16x8 h0 = *(const f16x8*)&A2[P][cl][g2 * 8];                     \
            f16x8 h1 = {};                                                          \
            if (g2 < 2) h1 = *(const f16x8*)&A2[P][cl][32 + g2 * 8];                \
            if (I >= 0) {                                                           \
                f32x4 z = {0.f, 0.f, 0.f, 0.f};                                     \
                z = __builtin_amdgcn_mfma_f32_16x16x32_f16(b2f[2], h0, z, 0, 0, 0); \
                z = __builtin_amdgcn_mfma_f32_16x16x32_f16(b2f[3], h1, z, 0, 0, 0); \
                z = __builtin_amdgcn_mfma_f32_16x16x32_f16(b2f[0], a0, z, 0, 0, 0); \
                z = __builtin_amdgcn_mfma_f32_16x16x32_f16(b2f[1], a1, z, 0, 0, 0); \
                acc2 = z;                                                           \
            }                                                                       \
            if (I < TT) {                                                           \
                f32x4 z = {0.f, 0.f, 0.f, 0.f};                                     \
                z = __builtin_amdgcn_mfma_f32_16x16x32_f16(b1f[0], a0, z, 0, 0, 0); \
                z = __builtin_amdgcn_mfma_f32_16x16x32_f16(b1f[1], a1, z, 0, 0, 0); \
                acc1 = z;                                                           \
            }                                                                       \
        }                                                                           \
        if (I >= 0) {                                                               \
            if (I < TT && doUpd) {                                                  \
                const half_t h2n = (half_t)cell_update(acc2, c2);                   \
                if (w == 12) AH[NP][cl][54 + g2] = h2n;  /* jj 48,49 -> AH pads */  \
                else         A2[NP][cl][jj]      = h2n;                             \
            }                                                                       \
            if (headLn && I >= 1) {                                                 \
                const int s = I - 1;                                                \
                obuf[(s >> 5) & 1][cl][(s & 31) * 2 + 0] = acc2[0];                 \
                obuf[(s >> 5) & 1][cl][(s & 31) * 2 + 1] = acc2[1];                 \
            }                                                                       \
        }                                                                           \
        if (I < TT) {                                                               \
            if (doUpd) AH[NP][cl][jj] = (half_t)cell_update(acc1, c1);              \
            if (w == 13 && lane < 16 && (I + 2) < TT) {                             \
                const int tn = I + 2;                                               \
                const float* xs = &xbuf[(tn >> 5) & 1][lane][(tn & 31) * 2];        \
                AH[NP][lane][50] = (half_t)xs[0];                                   \
                AH[NP][lane][51] = (half_t)xs[1];                                   \
            }                                                                       \
            if (hp) *(f32x4*)&xbuf[((I >> 5) + 1) & 1][xr][xq * 4] = xpre;          \
        }                                                                           \
        __syncthreads();                                                            \
    }

    // intervals I = -1 .. TT (1026 total = 513 pairs); first of each pair is odd
    for (int I = -1; I <= TT; ) {
        LSTM_STEP(1); ++I;
        LSTM_STEP(0); ++I;
    }
#undef LSTM_STEP

    // final flush: steps TT-32..TT-1 live in obuf[1]
    if (tid >= 768) {
        const f32x4 v = *(const f32x4*)&obuf[1][xr][xq * 4];
        *(f32x4*)(out + (size_t)(bg0 + xr) * (TT * 2) + (TT - KF) * 2 + xq * 4) = v;
    }
}

extern "C" void kernel_launch(void* const* d_in, const int* in_sizes, int n_in,
                              void* d_out, int out_size, void* d_ws, size_t ws_size,
                              hipStream_t stream) {
    const float* x     = (const float*)d_in[0];
    const float* W_ih1 = (const float*)d_in[1];
    const float* W_hh1 = (const float*)d_in[2];
    const float* b_ih1 = (const float*)d_in[3];
    const float* b_hh1 = (const float*)d_in[4];
    const float* W_ih2 = (const float*)d_in[5];
    const float* W_hh2 = (const float*)d_in[6];
    const float* b_ih2 = (const float*)d_in[7];
    const float* b_hh2 = (const float*)d_in[8];
    const float* W_lin = (const float*)d_in[9];
    const float* b_lin = (const float*)d_in[10];
    float* out = (float*)d_out;

    const int B = in_sizes[0] / (TT * 2);   // 4096
    const int blocks = B / NB;              // 256

    hipLaunchKernelGGL(lstm_mfma_kernel, dim3(blocks), dim3(1024), 0, stream,
                       x, W_ih1, W_hh1, b_ih1, b_hh1,
                       W_ih2, W_hh2, b_ih2, b_hh2, W_lin, b_lin, out);
}

// Round 11
// 813.501 us; speedup vs baseline: 1.0476x; 1.0476x over previous
//
#include <hip/hip_runtime.h>
#include <stdint.h>

#define DD 50
#define TT 1024
#define NB 16            // batch rows per block = MFMA M (full tile)
#define KF 32            // x-prefetch / out-flush chunk (steps)

typedef _Float16 half_t;
typedef __attribute__((ext_vector_type(8))) _Float16 f16x8;
typedef __attribute__((ext_vector_type(4))) float    f32x4;

#define AHS 72           // K=64: h1(50) | x(2) | 1@52 | pad — 144B rows
#define A2S 72           // K=64: h2(50) | pad
#define OBW 68           // obuf row stride (f32)

__device__ __forceinline__ float rcp_f(float x)  { return __builtin_amdgcn_rcpf(x); }
__device__ __forceinline__ float exp2_f(float x) { return __builtin_amdgcn_exp2f(x); }

// Fused LSTM cell update, common-denominator form: 5 exp2 + 2 rcp.
//   cn = [c*(1+a)(1+b) + (1+f_)(b-1)] / [(1+f_)(1+a)(1+b)]
//   h  = (e-1) / [(1+o_)(1+e)],  a=e^-i, b=e^{2g}, f_=e^-f, o_=e^-o, e=e^{2cn}
__device__ __forceinline__ float cell_update(const f32x4 acc, float& c) {
    const float a  = exp2_f(-1.4426950f * acc[0]);
    const float b  = exp2_f( 2.8853901f * acc[2]);
    const float f_ = exp2_f(-1.4426950f * acc[1]);
    const float uv = (1.0f + a) * (1.0f + b);
    const float wf = 1.0f + f_;
    const float cn = (c * uv + wf * (b - 1.0f)) * rcp_f(wf * uv);
    c = cn;
    const float o_ = exp2_f(-1.4426950f * acc[3]);
    const float e  = exp2_f( 2.8853901f * cn);
    return (e - 1.0f) * rcp_f((1.0f + o_) * (1.0f + e));
}

// 16 waves: waves 0-12 own ONE 16-col N-tile each (tile 12 = jj 48,49 + head
// cols 200,201); waves 13-15 are service-only. Gate columns interleaved
// col' = 4*jj + gate; MFMA with swapped operands (weights first):
// lane (cl,g2) of tile-wave w holds acc[r] = gate r of (b=cl, jj=4w+g2) —
// cell update fully per-lane. Shared-K trick: AH=[h1|x|1@52] feeds GEMM1 and
// GEMM2 kt0/1 (x rows zero in B2, biases at k=52); A2=[h2] feeds kt2/3.
// One barrier per pipelined interval; parity compile-time via 2x unroll.

__global__ __launch_bounds__(1024, 1)
void lstm_mfma_kernel(const float* __restrict__ x,
                      const float* __restrict__ W_ih1, const float* __restrict__ W_hh1,
                      const float* __restrict__ b_ih1, const float* __restrict__ b_hh1,
                      const float* __restrict__ W_ih2, const float* __restrict__ W_hh2,
                      const float* __restrict__ b_ih2, const float* __restrict__ b_hh2,
                      const float* __restrict__ W_lin, const float* __restrict__ b_lin,
                      float* __restrict__ out)
{
    const int tid  = threadIdx.x;
    const int lane = tid & 63;
    const int w    = tid >> 6;           // 0..15
    const int bg0  = blockIdx.x * NB;
    const int cl   = lane & 15;          // batch row (n)
    const int g2   = lane >> 4;          // k-group / jj offset within tile

    __shared__ half_t AH[2][NB][AHS];
    __shared__ half_t A2[2][NB][A2S];
    __shared__ float  obuf[2][NB][OBW];
    __shared__ float  xbuf[2][NB][KF*2];

    const bool isComp = (w < 13);
    const int  tile   = isComp ? w : 0;
    const int  jj     = tile * 4 + g2;
    const bool doUpd  = isComp && (jj < DD);
    const bool headLn = (w == 12) && (g2 == 2);    // lanes holding cols 200,201
    const int  xr     = (tid - 768) >> 4;          // service row   (tid>=768)
    const int  xq     = tid & 15;                  // service 16B quarter

    // ---- B fragments (one tile per wave) ----
    f16x8 b1f[2], b2f[4];
    {
        const int  colp  = tile * 16 + cl;
        const bool valid = isComp && (colp < 200);
        const bool headB = isComp && (colp >= 200) && (colp <= 201);
        const int  g     = (colp & 3) * DD + (colp >> 2);
        // B1 over AH-k: W_hh1 | W_ih1@50,51 | bias1@52
#pragma unroll
        for (int kt = 0; kt < 2; ++kt)
#pragma unroll
            for (int j = 0; j < 8; ++j) {
                const int k = kt * 32 + g2 * 8 + j;
                float v = 0.f;
                if (valid) {
                    if (k < DD)          v = W_hh1[g * DD + k];
                    else if (k < DD + 2) v = W_ih1[g * 2 + (k - DD)];
                    else if (k == 52)    v = b_ih1[g] + b_hh1[g];
                }
                b1f[kt][j] = (half_t)v;
            }
        // B2 kt0/1 over AH-k: W_ih2 | zeros@50,51 | bias2@52 (head: b_lin@52)
#pragma unroll
        for (int kt = 0; kt < 2; ++kt)
#pragma unroll
            for (int j = 0; j < 8; ++j) {
                const int k = kt * 32 + g2 * 8 + j;
                float v = 0.f;
                if (k < DD) {
                    if (valid) v = W_ih2[g * DD + k];
                } else if (k == 52) {
                    if (valid)      v = b_ih2[g] + b_hh2[g];
                    else if (headB) v = b_lin[colp - 200];
                }
                b2f[kt][j] = (half_t)v;
            }
        // B2 kt2/3 over A2-k (h2): W_hh2 (head: W_lin)
#pragma unroll
        for (int kt = 2; kt < 4; ++kt)
#pragma unroll
            for (int j = 0; j < 8; ++j) {
                const int kk = (kt - 2) * 32 + g2 * 8 + j;
                float v = 0.f;
                if (kk < DD) {
                    if (valid)      v = W_hh2[g * DD + kk];
                    else if (headB) v = W_lin[(colp - 200) * DD + kk];
                }
                b2f[kt][j] = (half_t)v;
            }
    }

    // ---- init ----
    for (int idx = tid; idx < 2 * NB * AHS; idx += 1024) ((half_t*)AH)[idx] = (half_t)0.f;
    for (int idx = tid; idx < 2 * NB * A2S; idx += 1024) ((half_t*)A2)[idx] = (half_t)0.f;
    if (tid >= 768) {
        const f32x4 v = *(const f32x4*)(x + (size_t)(bg0 + xr) * (TT * 2) + xq * 4);
        *(f32x4*)&xbuf[0][xr][xq * 4] = v;
    }
    __syncthreads();
    if (tid < NB) {
        AH[0][tid][52] = (half_t)1.0f; AH[1][tid][52] = (half_t)1.0f;
        AH[1][tid][50] = (half_t)xbuf[0][tid][0];    // x(0) at parity of I=-1
        AH[1][tid][51] = (half_t)xbuf[0][tid][1];
    }
    __syncthreads();

    float c1 = 0.f, c2 = 0.f;

#define LSTM_STEP(PC)                                                              \
    {                                                                               \
        constexpr int P = (PC), NP = (PC) ^ 1;                                      \
        if (((I & 31) == 1) && I >= 33 && tid >= 768) {                             \
            const f32x4 v = *(const f32x4*)&obuf[((I - 33) >> 5) & 1][xr][xq * 4];  \
            *(f32x4*)(out + (size_t)(bg0 + xr) * (TT * 2) + (I - 33) * 2 + xq * 4) = v; \
        }                                                                           \
        f32x4 xpre; bool hp = false;                                                \
        if (((I & 31) == 0) && I >= 0 && tid >= 768) {                              \
            const int chunk = (I >> 5) + 1;                                         \
            if (chunk < TT / KF) {                                                  \
                hp = true;                                                          \
                xpre = *(const f32x4*)(x + (size_t)(bg0 + xr) * (TT * 2) + chunk * (KF * 2) + xq * 4); \
            }                                                                       \
        }                                                                           \
        f32x4 acc1, acc2;                                                           \
        if (isComp) {                                                               \
            const f16x8 a0 = *(const f16x8*)&AH[P][cl][g2 * 8];                     \
            const f16x8 a1 = *(const f16x8*)&AH[P][cl][32 + g2 * 8];                \
            const f16x8 h0 = *(const f16x8*)&A2[P][cl][g2 * 8];                     \
            const f16x8 h1 = *(const f16x8*)&A2[P][cl][32 + g2 * 8];                \
            if (I >= 0) {                                                           \
                f32x4 z = {0.f, 0.f, 0.f, 0.f};                                     \
                z = __builtin_amdgcn_mfma_f32_16x16x32_f16(b2f[2], h0, z, 0, 0, 0); \
                z = __builtin_amdgcn_mfma_f32_16x16x32_f16(b2f[3], h1, z, 0, 0, 0); \
                z = __builtin_amdgcn_mfma_f32_16x16x32_f16(b2f[0], a0, z, 0, 0, 0); \
                z = __builtin_amdgcn_mfma_f32_16x16x32_f16(b2f[1], a1, z, 0, 0, 0); \
                acc2 = z;                                                           \
            }                                                                       \
            if (I < TT) {                                                           \
                f32x4 z = {0.f, 0.f, 0.f, 0.f};                                     \
                z = __builtin_amdgcn_mfma_f32_16x16x32_f16(b1f[0], a0, z, 0, 0, 0); \
                z = __builtin_amdgcn_mfma_f32_16x16x32_f16(b1f[1], a1, z, 0, 0, 0); \
                acc1 = z;                                                           \
            }                                                                       \
        }                                                                           \
        if (I >= 0) {                                                               \
            if (I < TT && doUpd) A2[NP][cl][jj] = (half_t)cell_update(acc2, c2);    \
            if (headLn && I >= 1) {                                                 \
                const int s = I - 1;                                                \
                obuf[(s >> 5) & 1][cl][(s & 31) * 2 + 0] = acc2[0];                 \
                obuf[(s >> 5) & 1][cl][(s & 31) * 2 + 1] = acc2[1];                 \
            }                                                                       \
        }                                                                           \
        if (I < TT) {                                                               \
            if (doUpd) AH[NP][cl][jj] = (half_t)cell_update(acc1, c1);              \
            if (w == 13 && lane < 16 && (I + 2) < TT) {                             \
                const int tn = I + 2;                                               \
                const float* xs = &xbuf[(tn >> 5) & 1][lane][(tn & 31) * 2];        \
                AH[NP][lane][50] = (half_t)xs[0];                                   \
                AH[NP][lane][51] = (half_t)xs[1];                                   \
            }                                                                       \
            if (hp) *(f32x4*)&xbuf[((I >> 5) + 1) & 1][xr][xq * 4] = xpre;          \
        }                                                                           \
        __syncthreads();                                                            \
    }

    // intervals I = -1 .. TT (1026 total = 513 pairs); first of each pair is odd
    for (int I = -1; I <= TT; ) {
        LSTM_STEP(1); ++I;
        LSTM_STEP(0); ++I;
    }
#undef LSTM_STEP

    // final flush: steps TT-32..TT-1 live in obuf[1]
    if (tid >= 768) {
        const f32x4 v = *(const f32x4*)&obuf[1][xr][xq * 4];
        *(f32x4*)(out + (size_t)(bg0 + xr) * (TT * 2) + (TT - KF) * 2 + xq * 4) = v;
    }
}

extern "C" void kernel_launch(void* const* d_in, const int* in_sizes, int n_in,
                              void* d_out, int out_size, void* d_ws, size_t ws_size,
                              hipStream_t stream) {
    const float* x     = (const float*)d_in[0];
    const float* W_ih1 = (const float*)d_in[1];
    const float* W_hh1 = (const float*)d_in[2];
    const float* b_ih1 = (const float*)d_in[3];
    const float* b_hh1 = (const float*)d_in[4];
    const float* W_ih2 = (const float*)d_in[5];
    const float* W_hh2 = (const float*)d_in[6];
    const float* b_ih2 = (const float*)d_in[7];
    const float* b_hh2 = (const float*)d_in[8];
    const float* W_lin = (const float*)d_in[9];
    const float* b_lin = (const float*)d_in[10];
    float* out = (float*)d_out;

    const int B = in_sizes[0] / (TT * 2);   // 4096
    const int blocks = B / NB;              // 256

    hipLaunchKernelGGL(lstm_mfma_kernel, dim3(blocks), dim3(1024), 0, stream,
                       x, W_ih1, W_hh1, b_ih1, b_hh1,
                       W_ih2, W_hh2, b_ih2, b_hh2, W_lin, b_lin, out);
}

// Round 12
// 795.533 us; speedup vs baseline: 1.0713x; 1.0226x over previous
//
#include <hip/hip_runtime.h>
#include <stdint.h>

#define DD 50
#define TT 1024
#define NB 16            // batch rows per block = MFMA M (full tile)
#define KF 32            // x-prefetch / out-flush chunk (steps)

typedef _Float16 half_t;
typedef __attribute__((ext_vector_type(8))) _Float16 f16x8;
typedef __attribute__((ext_vector_type(4))) float    f32x4;

#define AHS 72           // K=64: h1(50) | x(2) | 1@52 | pad — 144B rows (16B aligned)
#define A2S 72           // K=64: h2(50) | pad
#define OBW 68           // obuf row stride (f32)

__device__ __forceinline__ float rcp_f(float x)  { return __builtin_amdgcn_rcpf(x); }
__device__ __forceinline__ float exp2_f(float x) { return __builtin_amdgcn_exp2f(x); }

// Fused LSTM cell update, rcp-merged: 5 exp2 + 3 rcp per cell.
// (3-rcp form deliberately kept over the 2-rcp common-denominator variant:
//  the rcps are dependency-parallel here; r11 measured the "cheaper" 2-rcp
//  form 2.3% slower due to its longer serial chain.)
__device__ __forceinline__ float cell_update(const f32x4 acc, float& c) {
    const float a   = exp2_f(-1.4426950f * acc[0]);
    const float b   = exp2_f( 2.8853901f * acc[2]);
    const float t   = 1.0f + a;
    const float pig = (b - 1.0f) * rcp_f(t + t * b);
    const float pf  = rcp_f(1.0f + exp2_f(-1.4426950f * acc[1]));
    const float cn  = pf * c + pig;
    c = cn;
    const float o_  = exp2_f(-1.4426950f * acc[3]);
    const float e   = exp2_f( 2.8853901f * cn);
    const float t2  = 1.0f + o_;
    return (e - 1.0f) * rcp_f(t2 + t2 * e);
}

// 16 waves: waves 0-12 own ONE 16-col N-tile each (tile 12 = jj 48,49 + head
// cols 200,201); waves 13-15 are service-only. Gate columns interleaved
// col' = 4*jj + gate; MFMA with swapped operands (weights first):
// lane (cl,g2) of tile-wave w holds acc[r] = gate r of (b=cl, jj=4w+g2) —
// cell update fully per-lane. Shared-K trick: AH=[h1|x|1@52] feeds GEMM1 and
// GEMM2 kt0/1 (x rows zero in B2, biases at k=52); A2=[h2] feeds kt2/3.
// One barrier per pipelined interval; parity is compile-time via 2x unroll.

__global__ __launch_bounds__(1024, 1)
void lstm_mfma_kernel(const float* __restrict__ x,
                      const float* __restrict__ W_ih1, const float* __restrict__ W_hh1,
                      const float* __restrict__ b_ih1, const float* __restrict__ b_hh1,
                      const float* __restrict__ W_ih2, const float* __restrict__ W_hh2,
                      const float* __restrict__ b_ih2, const float* __restrict__ b_hh2,
                      const float* __restrict__ W_lin, const float* __restrict__ b_lin,
                      float* __restrict__ out)
{
    const int tid  = threadIdx.x;
    const int lane = tid & 63;
    const int w    = tid >> 6;           // 0..15
    const int bg0  = blockIdx.x * NB;
    const int cl   = lane & 15;          // batch row (n)
    const int g2   = lane >> 4;          // k-group / jj offset within tile

    __shared__ half_t AH[2][NB][AHS];
    __shared__ half_t A2[2][NB][A2S];
    __shared__ float  obuf[2][NB][OBW];
    __shared__ float  xbuf[2][NB][KF*2];

    const bool isComp = (w < 13);
    const int  tile   = isComp ? w : 0;
    const int  jj     = tile * 4 + g2;
    const bool doUpd  = isComp && (jj < DD);
    const bool headLn = (w == 12) && (g2 == 2);    // lanes holding cols 200,201
    const int  xr     = (tid - 768) >> 4;          // service row   (tid>=768)
    const int  xq     = tid & 15;                  // service 16B quarter

    // ---- B fragments (one tile per wave) ----
    f16x8 b1f[2], b2f[4];
    {
        const int  colp  = tile * 16 + cl;
        const bool valid = isComp && (colp < 200);
        const bool headB = isComp && (colp >= 200) && (colp <= 201);
        const int  g     = (colp & 3) * DD + (colp >> 2);
        // B1 over AH-k: W_hh1 | W_ih1@50,51 | bias1@52
#pragma unroll
        for (int kt = 0; kt < 2; ++kt)
#pragma unroll
            for (int j = 0; j < 8; ++j) {
                const int k = kt * 32 + g2 * 8 + j;
                float v = 0.f;
                if (valid) {
                    if (k < DD)          v = W_hh1[g * DD + k];
                    else if (k < DD + 2) v = W_ih1[g * 2 + (k - DD)];
                    else if (k == 52)    v = b_ih1[g] + b_hh1[g];
                }
                b1f[kt][j] = (half_t)v;
            }
        // B2 kt0/1 over AH-k: W_ih2 | zeros@50,51 | bias2@52 (head: b_lin@52)
#pragma unroll
        for (int kt = 0; kt < 2; ++kt)
#pragma unroll
            for (int j = 0; j < 8; ++j) {
                const int k = kt * 32 + g2 * 8 + j;
                float v = 0.f;
                if (k < DD) {
                    if (valid) v = W_ih2[g * DD + k];
                } else if (k == 52) {
                    if (valid)      v = b_ih2[g] + b_hh2[g];
                    else if (headB) v = b_lin[colp - 200];
                }
                b2f[kt][j] = (half_t)v;
            }
        // B2 kt2/3 over A2-k (h2): W_hh2 (head: W_lin)
#pragma unroll
        for (int kt = 2; kt < 4; ++kt)
#pragma unroll
            for (int j = 0; j < 8; ++j) {
                const int kk = (kt - 2) * 32 + g2 * 8 + j;
                float v = 0.f;
                if (kk < DD) {
                    if (valid)      v = W_hh2[g * DD + kk];
                    else if (headB) v = W_lin[(colp - 200) * DD + kk];
                }
                b2f[kt][j] = (half_t)v;
            }
    }

    // ---- init ----
    for (int idx = tid; idx < 2 * NB * AHS; idx += 1024) ((half_t*)AH)[idx] = (half_t)0.f;
    for (int idx = tid; idx < 2 * NB * A2S; idx += 1024) ((half_t*)A2)[idx] = (half_t)0.f;
    if (tid >= 768) {
        const f32x4 v = *(const f32x4*)(x + (size_t)(bg0 + xr) * (TT * 2) + xq * 4);
        *(f32x4*)&xbuf[0][xr][xq * 4] = v;
    }
    __syncthreads();
    if (tid < NB) {
        AH[0][tid][52] = (half_t)1.0f; AH[1][tid][52] = (half_t)1.0f;
        AH[1][tid][50] = (half_t)xbuf[0][tid][0];    // x(0) at parity of I=-1
        AH[1][tid][51] = (half_t)xbuf[0][tid][1];
    }
    __syncthreads();

    float c1 = 0.f, c2 = 0.f;

#define LSTM_STEP(PC)                                                              \
    {                                                                               \
        constexpr int P = (PC), NP = (PC) ^ 1;                                      \
        if (((I & 31) == 1) && I >= 33 && tid >= 768) {                             \
            const f32x4 v = *(const f32x4*)&obuf[((I - 33) >> 5) & 1][xr][xq * 4];  \
            *(f32x4*)(out + (size_t)(bg0 + xr) * (TT * 2) + (I - 33) * 2 + xq * 4) = v; \
        }                                                                           \
        f32x4 xpre; bool hp = false;                                                \
        if (((I & 31) == 0) && I >= 0 && tid >= 768) {                              \
            const int chunk = (I >> 5) + 1;                                         \
            if (chunk < TT / KF) {                                                  \
                hp = true;                                                          \
                xpre = *(const f32x4*)(x + (size_t)(bg0 + xr) * (TT * 2) + chunk * (KF * 2) + xq * 4); \
            }                                                                       \
        }                                                                           \
        f32x4 acc1, acc2;                                                           \
        if (isComp) {                                                               \
            const f16x8 a0 = *(const f16x8*)&AH[P][cl][g2 * 8];                     \
            const f16x8 a1 = *(const f16x8*)&AH[P][cl][32 + g2 * 8];                \
            const f16x8 h0 = *(const f16x8*)&A2[P][cl][g2 * 8];                     \
            const f16x8 h1 = *(const f16x8*)&A2[P][cl][32 + g2 * 8];                \
            if (I >= 0) {                                                           \
                f32x4 z = {0.f, 0.f, 0.f, 0.f};                                     \
                z = __builtin_amdgcn_mfma_f32_16x16x32_f16(b2f[2], h0, z, 0, 0, 0); \
                z = __builtin_amdgcn_mfma_f32_16x16x32_f16(b2f[3], h1, z, 0, 0, 0); \
                z = __builtin_amdgcn_mfma_f32_16x16x32_f16(b2f[0], a0, z, 0, 0, 0); \
                z = __builtin_amdgcn_mfma_f32_16x16x32_f16(b2f[1], a1, z, 0, 0, 0); \
                acc2 = z;                                                           \
            }                                                                       \
            if (I < TT) {                                                           \
                f32x4 z = {0.f, 0.f, 0.f, 0.f};                                     \
                z = __builtin_amdgcn_mfma_f32_16x16x32_f16(b1f[0], a0, z, 0, 0, 0); \
                z = __builtin_amdgcn_mfma_f32_16x16x32_f16(b1f[1], a1, z, 0, 0, 0); \
                acc1 = z;                                                           \
            }                                                                       \
        }                                                                           \
        if (I >= 0) {                                                               \
            if (I < TT && doUpd) A2[NP][cl][jj] = (half_t)cell_update(acc2, c2);    \
            if (headLn && I >= 1) {                                                 \
                const int s = I - 1;                                                \
                obuf[(s >> 5) & 1][cl][(s & 31) * 2 + 0] = acc2[0];                 \
                obuf[(s >> 5) & 1][cl][(s & 31) * 2 + 1] = acc2[1];                 \
            }                                                                       \
        }                                                                           \
        if (I < TT) {                                                               \
            if (doUpd) AH[NP][cl][jj] = (half_t)cell_update(acc1, c1);              \
            if (w == 13 && lane < 16 && (I + 2) < TT) {                             \
                const int tn = I + 2;                                               \
                const float* xs = &xbuf[(tn >> 5) & 1][lane][(tn & 31) * 2];        \
                AH[NP][lane][50] = (half_t)xs[0];                                   \
                AH[NP][lane][51] = (half_t)xs[1];                                   \
            }                                                                       \
            if (hp) *(f32x4*)&xbuf[((I >> 5) + 1) & 1][xr][xq * 4] = xpre;          \
        }                                                                           \
        __syncthreads();                                                            \
    }

    // intervals I = -1 .. TT (1026 total = 513 pairs); first of each pair is odd
    for (int I = -1; I <= TT; ) {
        LSTM_STEP(1); ++I;
        LSTM_STEP(0); ++I;
    }
#undef LSTM_STEP

    // final flush: steps TT-32..TT-1 live in obuf[1]
    if (tid >= 768) {
        const f32x4 v = *(const f32x4*)&obuf[1][xr][xq * 4];
        *(f32x4*)(out + (size_t)(bg0 + xr) * (TT * 2) + (TT - KF) * 2 + xq * 4) = v;
    }
}

extern "C" void kernel_launch(void* const* d_in, const int* in_sizes, int n_in,
                              void* d_out, int out_size, void* d_ws, size_t ws_size,
                              hipStream_t stream) {
    const float* x     = (const float*)d_in[0];
    const float* W_ih1 = (const float*)d_in[1];
    const float* W_hh1 = (const float*)d_in[2];
    const float* b_ih1 = (const float*)d_in[3];
    const float* b_hh1 = (const float*)d_in[4];
    const float* W_ih2 = (const float*)d_in[5];
    const float* W_hh2 = (const float*)d_in[6];
    const float* b_ih2 = (const float*)d_in[7];
    const float* b_hh2 = (const float*)d_in[8];
    const float* W_lin = (const float*)d_in[9];
    const float* b_lin = (const float*)d_in[10];
    float* out = (float*)d_out;

    const int B = in_sizes[0] / (TT * 2);   // 4096
    const int blocks = B / NB;              // 256

    hipLaunchKernelGGL(lstm_mfma_kernel, dim3(blocks), dim3(1024), 0, stream,
                       x, W_ih1, W_hh1, b_ih1, b_hh1,
                       W_ih2, W_hh2, b_ih2, b_hh2, W_lin, b_lin, out);
}